// Round 1
// baseline (389.289 us; speedup 1.0000x reference)
//
#include <hip/hip_runtime.h>

#define N_NODES   100000
#define N_EDGES   1600000
#define N_GRAPHS  256
#define D         32

// LDS accumulator is transposed: acc[d][g] at index d*N_GRAPHS + g.
// Bank = (d*256 + g) % 32 = g % 32 -> random g spreads across banks (~2-way, free).

__global__ void node_agg_kernel(const float* __restrict__ x,
                                const int* __restrict__ batch,
                                float* __restrict__ node_acc /* [G*D], g-major */) {
    __shared__ float lds[D * N_GRAPHS]; // 32 KB
    for (int i = threadIdx.x; i < D * N_GRAPHS; i += blockDim.x) lds[i] = 0.f;
    __syncthreads();

    const float4* __restrict__ x4 = (const float4*)x;
    const int total = N_NODES * (D / 4);           // 800000 float4 units
    const int per_block = (total + gridDim.x - 1) / gridDim.x;
    const int start = blockIdx.x * per_block;
    const int end   = min(start + per_block, total);

    for (int idx = start + (int)threadIdx.x; idx < end; idx += blockDim.x) {
        const int n = idx >> 3;          // node id   (D/4 = 8 chunks per node)
        const int c = idx & 7;           // float4 chunk within the row
        float4 v = x4[idx];              // coalesced
        const int g = batch[n];
        const int dbase = c * 4;
        unsafeAtomicAdd(&lds[(dbase + 0) * N_GRAPHS + g], v.x);
        unsafeAtomicAdd(&lds[(dbase + 1) * N_GRAPHS + g], v.y);
        unsafeAtomicAdd(&lds[(dbase + 2) * N_GRAPHS + g], v.z);
        unsafeAtomicAdd(&lds[(dbase + 3) * N_GRAPHS + g], v.w);
    }
    __syncthreads();

    // Flush: batch is sorted, so a block's node range spans few graphs ->
    // most LDS cells are exactly 0 and the atomic is skipped.
    for (int i = threadIdx.x; i < D * N_GRAPHS; i += blockDim.x) {
        const float v = lds[i];
        if (v != 0.f) {
            const int d = i >> 8;        // i / 256
            const int g = i & 255;       // i % 256
            unsafeAtomicAdd(&node_acc[g * D + d], v);
        }
    }
}

__global__ void edge_agg_kernel(const float* __restrict__ edge_attr,
                                const int* __restrict__ edge_src,  // edge_index row 0
                                const int* __restrict__ batch,
                                float* __restrict__ edge_acc /* [G*D], g-major */) {
    __shared__ float lds[D * N_GRAPHS]; // 32 KB
    for (int i = threadIdx.x; i < D * N_GRAPHS; i += blockDim.x) lds[i] = 0.f;
    __syncthreads();

    const float4* __restrict__ ea4 = (const float4*)edge_attr;
    const int total = N_EDGES * (D / 4);           // 12.8M float4 units
    const int per_block = (total + gridDim.x - 1) / gridDim.x;
    const int start = blockIdx.x * per_block;
    const int end   = min(start + per_block, total);

    for (int idx = start + (int)threadIdx.x; idx < end; idx += blockDim.x) {
        const int e = idx >> 3;
        const int c = idx & 7;
        float4 v = ea4[idx];             // coalesced: wave covers 1 KB contiguous
        const int g = batch[edge_src[e]]; // src coalesced (8-way broadcast), batch cached
        const int dbase = c * 4;
        unsafeAtomicAdd(&lds[(dbase + 0) * N_GRAPHS + g], v.x);
        unsafeAtomicAdd(&lds[(dbase + 1) * N_GRAPHS + g], v.y);
        unsafeAtomicAdd(&lds[(dbase + 2) * N_GRAPHS + g], v.z);
        unsafeAtomicAdd(&lds[(dbase + 3) * N_GRAPHS + g], v.w);
    }
    __syncthreads();

    for (int i = threadIdx.x; i < D * N_GRAPHS; i += blockDim.x) {
        const float v = lds[i];
        if (v != 0.f) {
            const int d = i >> 8;
            const int g = i & 255;
            unsafeAtomicAdd(&edge_acc[g * D + d], v);
        }
    }
}

// out[g][d] = relu(b[d] + sum_k concat(node_agg,edge_agg,u)[g][k] * W[k][d])
__global__ void mlp_kernel(const float* __restrict__ acc, // node_agg then edge_agg
                           const float* __restrict__ u,
                           const float* __restrict__ W,   // [3D][D]
                           const float* __restrict__ bias,
                           float* __restrict__ out) {
    __shared__ float Ws[3 * D * D]; // 12 KB
    for (int i = threadIdx.x; i < 3 * D * D; i += blockDim.x) Ws[i] = W[i];
    __syncthreads();

    const int t = blockIdx.x * blockDim.x + threadIdx.x; // 8192 threads
    const int g = t >> 5;
    const int d = t & 31;
    const float* __restrict__ nacc = acc;
    const float* __restrict__ eacc = acc + N_GRAPHS * D;

    float s = bias[d];
    #pragma unroll
    for (int k = 0; k < D; ++k) s += nacc[g * D + k] * Ws[k * D + d];
    #pragma unroll
    for (int k = 0; k < D; ++k) s += eacc[g * D + k] * Ws[(D + k) * D + d];
    #pragma unroll
    for (int k = 0; k < D; ++k) s += u[g * D + k] * Ws[(2 * D + k) * D + d];
    out[t] = fmaxf(s, 0.f);
}

extern "C" void kernel_launch(void* const* d_in, const int* in_sizes, int n_in,
                              void* d_out, int out_size, void* d_ws, size_t ws_size,
                              hipStream_t stream) {
    const float* x     = (const float*)d_in[0];
    const int*   ei    = (const int*)  d_in[1];  // [2, N_EDGES]; row 0 = src
    const float* ea    = (const float*)d_in[2];
    const float* u     = (const float*)d_in[3];
    const int*   batch = (const int*)  d_in[4];
    const float* W     = (const float*)d_in[5];
    const float* bias  = (const float*)d_in[6];
    float*       out   = (float*)d_out;

    float* acc = (float*)d_ws;                   // [2 * G * D] f32 = 64 KB
    hipMemsetAsync(d_ws, 0, 2 * N_GRAPHS * D * sizeof(float), stream);

    node_agg_kernel<<<256, 256, 0, stream>>>(x, batch, acc);
    edge_agg_kernel<<<256, 1024, 0, stream>>>(ea, ei, batch, acc + N_GRAPHS * D);
    mlp_kernel<<<32, 256, 0, stream>>>(acc, u, W, bias, out);
}